// Round 10
// baseline (421.094 us; speedup 1.0000x reference)
//
#include <hip/hip_runtime.h>
#include <hip/hip_bf16.h>
#include <math.h>

#define N_NODES 100000
#define N_EDGES 3200000
#define IN_F 256
#define OUT_F 64
#define LRELU_SLOPE 0.2f

#define NB 1563                         // buckets of 64 src nodes
#define CAP 3072                        // K5 per-chunk LDS edge capacity
                                        // (1 chunk/bucket; CAP probe r9 showed
                                        // chunking costs ~14us, LDS not binding)

// deterministic partition geometry (scan-ordered cnt2d)
#define NBLK2 256                       // partition blocks (8 XCDs x 32)
#define XG 32                           // blocks per XCD group
#define I4PB (N_EDGES / 4 / NBLK2)      // 3125 int4 per partition block
#define NE (NB * NBLK2)                 // 400,128 scan elements
#define S2PER ((NB + 255) / 256)        // 7 elems/thread in scan2

typedef __attribute__((ext_vector_type(8))) short bf16x8;
typedef __attribute__((ext_vector_type(4))) float f32x4;

// ---------------------------------------------------------------------------
// K0: W (256x64 fp32) -> wt (64x256 bf16, transposed). 64 blocks x 256 thr.
// ---------------------------------------------------------------------------
__global__ __launch_bounds__(256) void wt_kernel(
    const float* __restrict__ W, __hip_bfloat16* __restrict__ wt) {
  wt[blockIdx.x * 256 + threadIdx.x] =
      __float2bfloat16(W[threadIdx.x * 64 + blockIdx.x]);
}

// ---------------------------------------------------------------------------
// K1: h = X @ W via bf16 MFMA 16x16x32, fused s_src = h@a[:64],
// s_dst = h@a[64:]. No LDS (proven ~13 us faster than LDS-staged).
// ---------------------------------------------------------------------------
__global__ __launch_bounds__(256) void gemm_h_kernel(
    const float* __restrict__ in, const __hip_bfloat16* __restrict__ wt,
    const float* __restrict__ a, __hip_bfloat16* __restrict__ h,
    float* __restrict__ s_src, float* __restrict__ s_dst) {
  const int tid = threadIdx.x;
  const int w = tid >> 6, lane = tid & 63;
  const int lm = lane & 15, lg = lane >> 4;
  const int arow = blockIdx.x * 64 + w * 16 + lm;   // this lane's A row
  const bool rv = arow < N_NODES;
  const float* xrow = &in[(size_t)(rv ? arow : 0) * IN_F + lg * 8];

  f32x4 acc[4];
#pragma unroll
  for (int ct = 0; ct < 4; ++ct) acc[ct] = (f32x4){0.f, 0.f, 0.f, 0.f};

  const __hip_bfloat16* wbase = &wt[(size_t)lm * IN_F + lg * 8];

#pragma unroll
  for (int kt = 0; kt < 8; ++kt) {
    float4 xa = make_float4(0.f, 0.f, 0.f, 0.f);
    float4 xb = make_float4(0.f, 0.f, 0.f, 0.f);
    if (rv) {
      xa = *(const float4*)(xrow + kt * 32);
      xb = *(const float4*)(xrow + kt * 32 + 4);
    }
    union { __hip_bfloat16 s[8]; bf16x8 v; } u;
    u.s[0] = __float2bfloat16(xa.x); u.s[1] = __float2bfloat16(xa.y);
    u.s[2] = __float2bfloat16(xa.z); u.s[3] = __float2bfloat16(xa.w);
    u.s[4] = __float2bfloat16(xb.x); u.s[5] = __float2bfloat16(xb.y);
    u.s[6] = __float2bfloat16(xb.z); u.s[7] = __float2bfloat16(xb.w);
    const bf16x8 af = u.v;
#pragma unroll
    for (int ct = 0; ct < 4; ++ct) {
      bf16x8 bfr = *(const bf16x8*)(wbase + (size_t)ct * 16 * IN_F + kt * 32);
      acc[ct] = __builtin_amdgcn_mfma_f32_16x16x32_bf16(af, bfr, acc[ct],
                                                        0, 0, 0);
    }
  }

  float as[4], ad[4];
#pragma unroll
  for (int ct = 0; ct < 4; ++ct) {
    as[ct] = a[ct * 16 + lm];
    ad[ct] = a[OUT_F + ct * 16 + lm];
  }
#pragma unroll
  for (int reg = 0; reg < 4; ++reg) {
    const int row = blockIdx.x * 64 + w * 16 + lg * 4 + reg;
    float vs = 0.f, vd = 0.f;
    if (row < N_NODES) {
#pragma unroll
      for (int ct = 0; ct < 4; ++ct) {
        const float v = acc[ct][reg];
        h[(size_t)row * OUT_F + ct * 16 + lm] = __float2bfloat16(v);
        vs += v * as[ct];
        vd += v * ad[ct];
      }
    }
#pragma unroll
    for (int m = 1; m < 16; m <<= 1) {    // reduce within quad group
      vs += __shfl_xor(vs, m);
      vd += __shfl_xor(vd, m);
    }
    if (lm == 0 && row < N_NODES) {
      s_src[row] = vs;
      s_dst[row] = vd;
    }
  }
}

// ---------------------------------------------------------------------------
// K2: per-block LDS histogram over all NB buckets, written TRANSPOSED into
// scan order: cnt2d[bucket*NBLK2 + rank(block)]. rank groups blocks by XCD
// (b&7), so the 16 consecutive ranks sharing a 64B cnt2d line are all
// written by one XCD -> L2 merges partial lines. 512 thr, zero glb atomics.
// ---------------------------------------------------------------------------
__global__ __launch_bounds__(512) void hist2d_kernel(
    const int4* __restrict__ src4, int* __restrict__ cnt2d) {
  __shared__ int lh[NB];
  const int tid = threadIdx.x, b = blockIdx.x;
  const int rank = (b & 7) * XG + (b >> 3);
  for (int j = tid; j < NB; j += 512) lh[j] = 0;
  __syncthreads();
  const int base4 = b * I4PB;
#pragma unroll
  for (int i = 0; i < 7; ++i) {
    const int k = i * 512 + tid;
    if (k < I4PB) {
      const int4 s = src4[base4 + k];
      atomicAdd(&lh[s.x >> 6], 1);
      atomicAdd(&lh[s.y >> 6], 1);
      atomicAdd(&lh[s.z >> 6], 1);
      atomicAdd(&lh[s.w >> 6], 1);
    }
  }
  __syncthreads();
  for (int j = tid; j < NB; j += 512) cnt2d[j * NBLK2 + rank] = lh[j];
}

// ---------------------------------------------------------------------------
// K3 (3 launches): hierarchical exclusive scan, fully coalesced.
// scan1 block j == bucket j (256 contiguous rank entries); scan2 scans the
// 1563 bucket totals and emits bstart directly; scan3 adds bucket bases.
// ---------------------------------------------------------------------------
__global__ __launch_bounds__(256) void scan1_kernel(
    int* __restrict__ cnt2d, int* __restrict__ pt) {
  __shared__ int ws[4];
  const int tid = threadIdx.x, lane = tid & 63, wv = tid >> 6;
  const int o = blockIdx.x * 256 + tid;
  const int v = cnt2d[o];
  int incl = v;
#pragma unroll
  for (int off = 1; off < 64; off <<= 1) {
    const int t = __shfl_up(incl, off);
    if (lane >= off) incl += t;
  }
  if (lane == 63) ws[wv] = incl;
  __syncthreads();
  int base = 0;
#pragma unroll
  for (int k = 0; k < 4; ++k)
    if (k < wv) base += ws[k];
  cnt2d[o] = base + incl - v;                     // exclusive within bucket
  if (tid == 255) pt[blockIdx.x] = base + incl;   // bucket total
}

__global__ __launch_bounds__(256) void scan2_kernel(
    int* __restrict__ pt, int* __restrict__ bstart) {
  __shared__ int ts[256];
  const int t = threadIdx.x;
  int local[S2PER];
  int sum = 0;
#pragma unroll
  for (int k = 0; k < S2PER; ++k) {
    const int o = t * S2PER + k;
    const int v = (o < NB) ? pt[o] : 0;
    local[k] = sum;
    sum += v;
  }
  ts[t] = sum;
  __syncthreads();
  for (int off = 1; off < 256; off <<= 1) {
    int tv = (t >= off) ? ts[t - off] : 0;
    __syncthreads();
    ts[t] += tv;
    __syncthreads();
  }
  const int ex = (t > 0) ? ts[t - 1] : 0;
#pragma unroll
  for (int k = 0; k < S2PER; ++k) {
    const int o = t * S2PER + k;
    if (o < NB) {
      pt[o] = ex + local[k];
      bstart[o] = ex + local[k];
    }
  }
  if (t == 0) bstart[NB] = N_EDGES;
}

__global__ __launch_bounds__(256) void scan3_kernel(
    int* __restrict__ cnt2d, const int* __restrict__ pt) {
  const int o = blockIdx.x * 256 + threadIdx.x;
  cnt2d[o] += pt[blockIdx.x];          // block j == bucket j
}

// ---------------------------------------------------------------------------
// K4: deterministic-base scatter. Block b loads its scanned bases
// cnt2d[j*NBLK2 + rank(b)], bumps with LDS atomics, writes staged. Per
// (block,bucket) run ~8 edges; per XCD-group run ~1KB contiguous -> each
// XCD's staged working set ~1.6MB, L2-absorbed. Zero global atomics.
// ---------------------------------------------------------------------------
__global__ __launch_bounds__(512) void scatter2_kernel(
    const int4* __restrict__ src4, const int4* __restrict__ dst4,
    const int* __restrict__ cnt2d, unsigned int* __restrict__ staged) {
  __shared__ int base[NB];
  const int tid = threadIdx.x, b = blockIdx.x;
  const int rank = (b & 7) * XG + (b >> 3);
  for (int j = tid; j < NB; j += 512) base[j] = cnt2d[j * NBLK2 + rank];
  __syncthreads();
  const int base4 = b * I4PB;
#pragma unroll
  for (int i = 0; i < 7; ++i) {
    const int k = i * 512 + tid;
    if (k < I4PB) {
      const int4 s = src4[base4 + k];
      const int4 d = dst4[base4 + k];
      int p;
      p = atomicAdd(&base[s.x >> 6], 1);
      staged[p] = ((unsigned)(s.x & 63) << 17) | (unsigned)d.x;
      p = atomicAdd(&base[s.y >> 6], 1);
      staged[p] = ((unsigned)(s.y & 63) << 17) | (unsigned)d.y;
      p = atomicAdd(&base[s.z >> 6], 1);
      staged[p] = ((unsigned)(s.z & 63) << 17) | (unsigned)d.z;
      p = atomicAdd(&base[s.w >> 6], 1);
      staged[p] = ((unsigned)(s.w & 63) << 17) | (unsigned)d.w;
    }
  }
}

// ---------------------------------------------------------------------------
// K5: one block per bucket. LDS counting sort by local src (phases A/B as
// the proven 152us version, CAP 3072), then phase C with DEPTH-2 SOFTWARE
// PIPELINE: batch k+1's eds reads + h-gathers issued before batch k's
// compute -> 8 outstanding h loads per wave instead of 4 (phase C is
// latency-bound on L2-miss h gathers; occupancy probe r9 showed TLP fixed).
// Named registers only (no runtime-indexed arrays -> no scratch).
// ---------------------------------------------------------------------------
__global__ __launch_bounds__(256) void sort_aggregate_kernel(
    const int* __restrict__ bstart, const unsigned int* __restrict__ staged,
    const float* __restrict__ s_src, const float* __restrict__ s_dst,
    const __hip_bfloat16* __restrict__ h, float* __restrict__ out) {
  __shared__ uint2 eds[CAP];            // 24 KB
  __shared__ float ssrc[64];
  __shared__ int lcnt[64];
  __shared__ int lstart[65];
  __shared__ int lcur[64];

  const int b = blockIdx.x;
  const int tid = threadIdx.x;
  const int lane = tid & 63;
  const int wv = tid >> 6;
  const int node0 = b << 6;

  if (tid < 64)
    ssrc[tid] = (node0 + tid < N_NODES) ? s_src[node0 + tid] : 0.f;

  const int e0 = bstart[b];
  const int e1 = bstart[b + 1];

  float acc[16], rsn[16];
#pragma unroll
  for (int j = 0; j < 16; ++j) { acc[j] = 0.f; rsn[j] = 0.f; }

  for (int c0 = e0; c0 < e1; c0 += CAP) {
    const int cc = min(CAP, e1 - c0);
    __syncthreads();
    if (tid < 64) lcnt[tid] = 0;
    __syncthreads();

    // phase A: histogram of local src
    for (int i = tid; i < cc; i += 256)
      atomicAdd(&lcnt[staged[c0 + i] >> 17], 1);
    __syncthreads();

    // wave-0 scan of the 64 counters
    if (tid < 64) {
      int v = lcnt[tid];
#pragma unroll
      for (int off = 1; off < 64; off <<= 1) {
        int tv = __shfl_up(v, off);
        if (lane >= off) v += tv;
      }
      lstart[tid + 1] = v;
      if (tid == 0) lstart[0] = 0;
      lcur[tid] = v - lcnt[tid];
    }
    __syncthreads();

    // phase B: ee once per edge, scatter sorted into LDS (packed b64)
    for (int i = tid; i < cc; i += 256) {
      const unsigned pk = staged[c0 + i];
      const int ls = (int)(pk >> 17);
      const int d = (int)(pk & 0x1FFFFu);
      const float sc = ssrc[ls] + s_dst[d];
      const float lr = sc > 0.f ? sc : LRELU_SLOPE * sc;
      const float ev = __expf(-lr);
      const int p = atomicAdd(&lcur[ls], 1);
      eds[p] = make_uint2((unsigned)d, __float_as_uint(ev));
    }
    __syncthreads();

    // phase C: wave wv accumulates its 16 nodes; depth-2 pipelined 4-batch
#pragma unroll
    for (int j = 0; j < 16; ++j) {
      const int n = wv + 4 * j;
      const int iend = lstart[n + 1];
      int i = lstart[n];
      float p0 = 0.f, p1 = 0.f, rv = 0.f;
      const int nb4 = (iend - i) >> 2;
      if (nb4 > 0) {
        // prologue: load batch 0
        uint2 a0 = eds[i + 0], a1 = eds[i + 1];
        uint2 a2 = eds[i + 2], a3 = eds[i + 3];
        float g0 = __bfloat162float(h[(size_t)a0.x * OUT_F + lane]);
        float g1 = __bfloat162float(h[(size_t)a1.x * OUT_F + lane]);
        float g2 = __bfloat162float(h[(size_t)a2.x * OUT_F + lane]);
        float g3 = __bfloat162float(h[(size_t)a3.x * OUT_F + lane]);
        i += 4;
        for (int t = 1; t < nb4; ++t, i += 4) {
          // issue next batch's loads before computing current
          const uint2 b0 = eds[i + 0], b1 = eds[i + 1];
          const uint2 b2 = eds[i + 2], b3 = eds[i + 3];
          const float n0 = __bfloat162float(h[(size_t)b0.x * OUT_F + lane]);
          const float n1 = __bfloat162float(h[(size_t)b1.x * OUT_F + lane]);
          const float n2 = __bfloat162float(h[(size_t)b2.x * OUT_F + lane]);
          const float n3 = __bfloat162float(h[(size_t)b3.x * OUT_F + lane]);
          const float v0 = __uint_as_float(a0.y), v1 = __uint_as_float(a1.y);
          const float v2 = __uint_as_float(a2.y), v3 = __uint_as_float(a3.y);
          p0 += v0 * g0 + v2 * g2;
          p1 += v1 * g1 + v3 * g3;
          rv += (v0 + v1) + (v2 + v3);
          a0 = b0; a1 = b1; a2 = b2; a3 = b3;
          g0 = n0; g1 = n1; g2 = n2; g3 = n3;
        }
        // epilogue: compute last in-flight batch
        const float v0 = __uint_as_float(a0.y), v1 = __uint_as_float(a1.y);
        const float v2 = __uint_as_float(a2.y), v3 = __uint_as_float(a3.y);
        p0 += v0 * g0 + v2 * g2;
        p1 += v1 * g1 + v3 * g3;
        rv += (v0 + v1) + (v2 + v3);
      }
      for (; i < iend; ++i) {
        const uint2 q0 = eds[i];
        const float v0 = __uint_as_float(q0.y);
        p0 += v0 * __bfloat162float(h[(size_t)q0.x * OUT_F + lane]);
        rv += v0;
      }
      acc[j] += p0 + p1;
      rsn[j] += rv;
    }
  }

  // epilogue: out = elu(acc / rowsum)
#pragma unroll
  for (int j = 0; j < 16; ++j) {
    const int node = node0 + wv + 4 * j;
    if (node < N_NODES) {
      const float v = acc[j] / rsn[j];
      out[(size_t)node * OUT_F + lane] = v > 0.f ? v : expm1f(v);
    }
  }
}

extern "C" void kernel_launch(void* const* d_in, const int* in_sizes, int n_in,
                              void* d_out, int out_size, void* d_ws, size_t ws_size,
                              hipStream_t stream) {
  const float* in = (const float*)d_in[0];
  const int* edge = (const int*)d_in[1];
  const float* W = (const float*)d_in[2];
  const float* a = (const float*)d_in[3];
  float* out = (float*)d_out;

  const int4* src4 = (const int4*)edge;
  const int4* dst4 = (const int4*)(edge + N_EDGES);

  // workspace: identical to proven round-0 layout (26,639,100 B).
  // bctr region unused (kept for layout stability).
  char* p = (char*)d_ws;
  __hip_bfloat16* h = (__hip_bfloat16*)p;  p += (size_t)N_NODES * OUT_F * 2;
  float* s_src = (float*)p;                p += (size_t)N_NODES * 4;
  float* s_dst = (float*)p;                p += (size_t)N_NODES * 4;
  unsigned int* staged = (unsigned int*)p; p += (size_t)N_EDGES * 4;
  int* bctr = (int*)p;                     p += (size_t)(NB * 32) * 4;
  int* bstart = (int*)p;                   p += (size_t)(NB + 1) * 4 + 12;
  __hip_bfloat16* wt = (__hip_bfloat16*)p; p += (size_t)OUT_F * IN_F * 2;
  (void)bctr;

  // scratch in d_out (fully overwritten by sort_aggregate afterwards):
  // cnt2d NB*NBLK2*4 = 1.6 MB at offset 0, pt at offset 8 MB (6.3 KB).
  int* cnt2d = (int*)d_out;
  int* pt = (int*)((char*)d_out + (size_t)8 * 1024 * 1024);

  wt_kernel<<<OUT_F, 256, 0, stream>>>(W, wt);
  gemm_h_kernel<<<(N_NODES + 63) / 64, 256, 0, stream>>>(in, wt, a, h, s_src,
                                                         s_dst);
  hist2d_kernel<<<NBLK2, 512, 0, stream>>>(src4, cnt2d);
  scan1_kernel<<<NB, 256, 0, stream>>>(cnt2d, pt);
  scan2_kernel<<<1, 256, 0, stream>>>(pt, bstart);
  scan3_kernel<<<NB, 256, 0, stream>>>(cnt2d, pt);
  scatter2_kernel<<<NBLK2, 512, 0, stream>>>(src4, dst4, cnt2d, staged);
  sort_aggregate_kernel<<<NB, 256, 0, stream>>>(bstart, staged, s_src, s_dst,
                                                h, out);
}

// Round 11
// 351.728 us; speedup vs baseline: 1.1972x; 1.1972x over previous
//
#include <hip/hip_runtime.h>
#include <hip/hip_bf16.h>
#include <math.h>

#define N_NODES 100000
#define N_EDGES 3200000
#define IN_F 256
#define OUT_F 64
#define LRELU_SLOPE 0.2f

#define NB 1563                         // buckets of 64 src nodes
#define CAP 3072                        // K5 per-chunk LDS edge capacity

// deterministic partition geometry (scan-ordered cnt2d)
#define NBLK2 256                       // partition blocks (8 XCDs x 32)
#define XG 32                           // blocks per XCD group
#define I4PB (N_EDGES / 4 / NBLK2)      // 3125 int4 per partition block
#define NE (NB * NBLK2)                 // 400,128 scan elements
#define S2PER ((NB + 255) / 256)        // 7 elems/thread in scan2

typedef __attribute__((ext_vector_type(8))) short bf16x8;
typedef __attribute__((ext_vector_type(4))) float f32x4;

// ---------------------------------------------------------------------------
// K0: W (256x64 fp32) -> wt (64x256 bf16, transposed). 64 blocks x 256 thr.
// ---------------------------------------------------------------------------
__global__ __launch_bounds__(256) void wt_kernel(
    const float* __restrict__ W, __hip_bfloat16* __restrict__ wt) {
  wt[blockIdx.x * 256 + threadIdx.x] =
      __float2bfloat16(W[threadIdx.x * 64 + blockIdx.x]);
}

// ---------------------------------------------------------------------------
// K1: h = X @ W via bf16 MFMA 16x16x32, fused s_src = h@a[:64],
// s_dst = h@a[64:]. No LDS (proven ~13 us faster than LDS-staged).
// ---------------------------------------------------------------------------
__global__ __launch_bounds__(256) void gemm_h_kernel(
    const float* __restrict__ in, const __hip_bfloat16* __restrict__ wt,
    const float* __restrict__ a, __hip_bfloat16* __restrict__ h,
    float* __restrict__ s_src, float* __restrict__ s_dst) {
  const int tid = threadIdx.x;
  const int w = tid >> 6, lane = tid & 63;
  const int lm = lane & 15, lg = lane >> 4;
  const int arow = blockIdx.x * 64 + w * 16 + lm;   // this lane's A row
  const bool rv = arow < N_NODES;
  const float* xrow = &in[(size_t)(rv ? arow : 0) * IN_F + lg * 8];

  f32x4 acc[4];
#pragma unroll
  for (int ct = 0; ct < 4; ++ct) acc[ct] = (f32x4){0.f, 0.f, 0.f, 0.f};

  const __hip_bfloat16* wbase = &wt[(size_t)lm * IN_F + lg * 8];

#pragma unroll
  for (int kt = 0; kt < 8; ++kt) {
    float4 xa = make_float4(0.f, 0.f, 0.f, 0.f);
    float4 xb = make_float4(0.f, 0.f, 0.f, 0.f);
    if (rv) {
      xa = *(const float4*)(xrow + kt * 32);
      xb = *(const float4*)(xrow + kt * 32 + 4);
    }
    union { __hip_bfloat16 s[8]; bf16x8 v; } u;
    u.s[0] = __float2bfloat16(xa.x); u.s[1] = __float2bfloat16(xa.y);
    u.s[2] = __float2bfloat16(xa.z); u.s[3] = __float2bfloat16(xa.w);
    u.s[4] = __float2bfloat16(xb.x); u.s[5] = __float2bfloat16(xb.y);
    u.s[6] = __float2bfloat16(xb.z); u.s[7] = __float2bfloat16(xb.w);
    const bf16x8 af = u.v;
#pragma unroll
    for (int ct = 0; ct < 4; ++ct) {
      bf16x8 bfr = *(const bf16x8*)(wbase + (size_t)ct * 16 * IN_F + kt * 32);
      acc[ct] = __builtin_amdgcn_mfma_f32_16x16x32_bf16(af, bfr, acc[ct],
                                                        0, 0, 0);
    }
  }

  float as[4], ad[4];
#pragma unroll
  for (int ct = 0; ct < 4; ++ct) {
    as[ct] = a[ct * 16 + lm];
    ad[ct] = a[OUT_F + ct * 16 + lm];
  }
#pragma unroll
  for (int reg = 0; reg < 4; ++reg) {
    const int row = blockIdx.x * 64 + w * 16 + lg * 4 + reg;
    float vs = 0.f, vd = 0.f;
    if (row < N_NODES) {
#pragma unroll
      for (int ct = 0; ct < 4; ++ct) {
        const float v = acc[ct][reg];
        h[(size_t)row * OUT_F + ct * 16 + lm] = __float2bfloat16(v);
        vs += v * as[ct];
        vd += v * ad[ct];
      }
    }
#pragma unroll
    for (int m = 1; m < 16; m <<= 1) {    // reduce within quad group
      vs += __shfl_xor(vs, m);
      vd += __shfl_xor(vd, m);
    }
    if (lm == 0 && row < N_NODES) {
      s_src[row] = vs;
      s_dst[row] = vd;
    }
  }
}

// ---------------------------------------------------------------------------
// K2: per-block LDS histogram over all NB buckets, written TRANSPOSED into
// scan order: cnt2d[bucket*NBLK2 + rank(block)]. rank groups blocks by XCD
// (b&7), so the 16 consecutive ranks sharing a 64B cnt2d line are all
// written by one XCD -> L2 merges partial lines. 512 thr, zero glb atomics.
// ---------------------------------------------------------------------------
__global__ __launch_bounds__(512) void hist2d_kernel(
    const int4* __restrict__ src4, int* __restrict__ cnt2d) {
  __shared__ int lh[NB];
  const int tid = threadIdx.x, b = blockIdx.x;
  const int rank = (b & 7) * XG + (b >> 3);
  for (int j = tid; j < NB; j += 512) lh[j] = 0;
  __syncthreads();
  const int base4 = b * I4PB;
#pragma unroll
  for (int i = 0; i < 7; ++i) {
    const int k = i * 512 + tid;
    if (k < I4PB) {
      const int4 s = src4[base4 + k];
      atomicAdd(&lh[s.x >> 6], 1);
      atomicAdd(&lh[s.y >> 6], 1);
      atomicAdd(&lh[s.z >> 6], 1);
      atomicAdd(&lh[s.w >> 6], 1);
    }
  }
  __syncthreads();
  for (int j = tid; j < NB; j += 512) cnt2d[j * NBLK2 + rank] = lh[j];
}

// ---------------------------------------------------------------------------
// K3 (2 launches; scan3 fused into scatter2): scan1 block j == bucket j
// (256 contiguous rank entries -> exclusive-within-bucket); scan2 scans the
// 1563 bucket totals into pt (bucket bases) and emits bstart.
// ---------------------------------------------------------------------------
__global__ __launch_bounds__(256) void scan1_kernel(
    int* __restrict__ cnt2d, int* __restrict__ pt) {
  __shared__ int ws[4];
  const int tid = threadIdx.x, lane = tid & 63, wv = tid >> 6;
  const int o = blockIdx.x * 256 + tid;
  const int v = cnt2d[o];
  int incl = v;
#pragma unroll
  for (int off = 1; off < 64; off <<= 1) {
    const int t = __shfl_up(incl, off);
    if (lane >= off) incl += t;
  }
  if (lane == 63) ws[wv] = incl;
  __syncthreads();
  int base = 0;
#pragma unroll
  for (int k = 0; k < 4; ++k)
    if (k < wv) base += ws[k];
  cnt2d[o] = base + incl - v;                     // exclusive within bucket
  if (tid == 255) pt[blockIdx.x] = base + incl;   // bucket total
}

__global__ __launch_bounds__(256) void scan2_kernel(
    int* __restrict__ pt, int* __restrict__ bstart) {
  __shared__ int ts[256];
  const int t = threadIdx.x;
  int local[S2PER];
  int sum = 0;
#pragma unroll
  for (int k = 0; k < S2PER; ++k) {
    const int o = t * S2PER + k;
    const int v = (o < NB) ? pt[o] : 0;
    local[k] = sum;
    sum += v;
  }
  ts[t] = sum;
  __syncthreads();
  for (int off = 1; off < 256; off <<= 1) {
    int tv = (t >= off) ? ts[t - off] : 0;
    __syncthreads();
    ts[t] += tv;
    __syncthreads();
  }
  const int ex = (t > 0) ? ts[t - 1] : 0;
#pragma unroll
  for (int k = 0; k < S2PER; ++k) {
    const int o = t * S2PER + k;
    if (o < NB) {
      pt[o] = ex + local[k];
      bstart[o] = ex + local[k];
    }
  }
  if (t == 0) bstart[NB] = N_EDGES;
}

// ---------------------------------------------------------------------------
// K4: deterministic-base scatter (scan3 fused: base = bucket base pt[j] +
// exclusive-within-bucket cnt2d[j*NBLK2+rank]). Bumps with LDS atomics,
// writes staged. Per XCD-group staged runs ~1KB contiguous -> L2-absorbed.
// Zero global atomics.
// ---------------------------------------------------------------------------
__global__ __launch_bounds__(512) void scatter2_kernel(
    const int4* __restrict__ src4, const int4* __restrict__ dst4,
    const int* __restrict__ cnt2d, const int* __restrict__ pt,
    unsigned int* __restrict__ staged) {
  __shared__ int base[NB];
  const int tid = threadIdx.x, b = blockIdx.x;
  const int rank = (b & 7) * XG + (b >> 3);
  for (int j = tid; j < NB; j += 512)
    base[j] = cnt2d[j * NBLK2 + rank] + pt[j];
  __syncthreads();
  const int base4 = b * I4PB;
#pragma unroll
  for (int i = 0; i < 7; ++i) {
    const int k = i * 512 + tid;
    if (k < I4PB) {
      const int4 s = src4[base4 + k];
      const int4 d = dst4[base4 + k];
      int p;
      p = atomicAdd(&base[s.x >> 6], 1);
      staged[p] = ((unsigned)(s.x & 63) << 17) | (unsigned)d.x;
      p = atomicAdd(&base[s.y >> 6], 1);
      staged[p] = ((unsigned)(s.y & 63) << 17) | (unsigned)d.y;
      p = atomicAdd(&base[s.z >> 6], 1);
      staged[p] = ((unsigned)(s.z & 63) << 17) | (unsigned)d.z;
      p = atomicAdd(&base[s.w >> 6], 1);
      staged[p] = ((unsigned)(s.w & 63) << 17) | (unsigned)d.w;
    }
  }
}

// ---------------------------------------------------------------------------
// K5: one block per bucket, now 512 THREADS (8 waves, wave owns 8 nodes).
// Residency analysis (r5/r9/r10): blocks/CU = min(grid 6.1, LDS, VGPR);
// 4-wave blocks gave 24 waves/CU; 8-wave blocks demand 49 -> HW cap 32
// waves/CU (+33% latency hiding). acc[8]/rsn[8] keeps VGPR well under the
// 64-reg cliff (r10: 68 VGPR -> 16 waves, regression). Phase C = proven
// simple 4-batch (depth-2 pipeline reverted).
// ---------------------------------------------------------------------------
__global__ __launch_bounds__(512) void sort_aggregate_kernel(
    const int* __restrict__ bstart, const unsigned int* __restrict__ staged,
    const float* __restrict__ s_src, const float* __restrict__ s_dst,
    const __hip_bfloat16* __restrict__ h, float* __restrict__ out) {
  __shared__ uint2 eds[CAP];            // 24 KB
  __shared__ float ssrc[64];
  __shared__ int lcnt[64];
  __shared__ int lstart[65];
  __shared__ int lcur[64];

  const int b = blockIdx.x;
  const int tid = threadIdx.x;
  const int lane = tid & 63;
  const int wv = tid >> 6;              // 0..7
  const int node0 = b << 6;

  if (tid < 64)
    ssrc[tid] = (node0 + tid < N_NODES) ? s_src[node0 + tid] : 0.f;

  const int e0 = bstart[b];
  const int e1 = bstart[b + 1];

  float acc[8], rsn[8];
#pragma unroll
  for (int j = 0; j < 8; ++j) { acc[j] = 0.f; rsn[j] = 0.f; }

  for (int c0 = e0; c0 < e1; c0 += CAP) {
    const int cc = min(CAP, e1 - c0);
    __syncthreads();
    if (tid < 64) lcnt[tid] = 0;
    __syncthreads();

    // phase A: histogram of local src
    for (int i = tid; i < cc; i += 512)
      atomicAdd(&lcnt[staged[c0 + i] >> 17], 1);
    __syncthreads();

    // wave-0 scan of the 64 counters
    if (tid < 64) {
      int v = lcnt[tid];
#pragma unroll
      for (int off = 1; off < 64; off <<= 1) {
        int tv = __shfl_up(v, off);
        if (lane >= off) v += tv;
      }
      lstart[tid + 1] = v;
      if (tid == 0) lstart[0] = 0;
      lcur[tid] = v - lcnt[tid];
    }
    __syncthreads();

    // phase B: ee once per edge, scatter sorted into LDS (packed b64)
    for (int i = tid; i < cc; i += 512) {
      const unsigned pk = staged[c0 + i];
      const int ls = (int)(pk >> 17);
      const int d = (int)(pk & 0x1FFFFu);
      const float sc = ssrc[ls] + s_dst[d];
      const float lr = sc > 0.f ? sc : LRELU_SLOPE * sc;
      const float ev = __expf(-lr);
      const int p = atomicAdd(&lcur[ls], 1);
      eds[p] = make_uint2((unsigned)d, __float_as_uint(ev));
    }
    __syncthreads();

    // phase C: wave wv accumulates its 8 nodes in registers
#pragma unroll
    for (int j = 0; j < 8; ++j) {
      const int n = wv + 8 * j;
      const int iend = lstart[n + 1];
      int i = lstart[n];
      float p0 = 0.f, p1 = 0.f, rv = 0.f;
      for (; i + 4 <= iend; i += 4) {
        const uint2 q0 = eds[i + 0], q1 = eds[i + 1];
        const uint2 q2 = eds[i + 2], q3 = eds[i + 3];
        const float v0 = __uint_as_float(q0.y), v1 = __uint_as_float(q1.y);
        const float v2 = __uint_as_float(q2.y), v3 = __uint_as_float(q3.y);
        const float h0 = __bfloat162float(h[(size_t)q0.x * OUT_F + lane]);
        const float h1 = __bfloat162float(h[(size_t)q1.x * OUT_F + lane]);
        const float h2 = __bfloat162float(h[(size_t)q2.x * OUT_F + lane]);
        const float h3 = __bfloat162float(h[(size_t)q3.x * OUT_F + lane]);
        p0 += v0 * h0 + v2 * h2;
        p1 += v1 * h1 + v3 * h3;
        rv += (v0 + v1) + (v2 + v3);
      }
      for (; i < iend; ++i) {
        const uint2 q0 = eds[i];
        const float v0 = __uint_as_float(q0.y);
        p0 += v0 * __bfloat162float(h[(size_t)q0.x * OUT_F + lane]);
        rv += v0;
      }
      acc[j] += p0 + p1;
      rsn[j] += rv;
    }
  }

  // epilogue: out = elu(acc / rowsum)
#pragma unroll
  for (int j = 0; j < 8; ++j) {
    const int node = node0 + wv + 8 * j;
    if (node < N_NODES) {
      const float v = acc[j] / rsn[j];
      out[(size_t)node * OUT_F + lane] = v > 0.f ? v : expm1f(v);
    }
  }
}

extern "C" void kernel_launch(void* const* d_in, const int* in_sizes, int n_in,
                              void* d_out, int out_size, void* d_ws, size_t ws_size,
                              hipStream_t stream) {
  const float* in = (const float*)d_in[0];
  const int* edge = (const int*)d_in[1];
  const float* W = (const float*)d_in[2];
  const float* a = (const float*)d_in[3];
  float* out = (float*)d_out;

  const int4* src4 = (const int4*)edge;
  const int4* dst4 = (const int4*)(edge + N_EDGES);

  // workspace: identical to proven round-0 layout (26,639,100 B).
  // bctr region unused (kept for layout stability).
  char* p = (char*)d_ws;
  __hip_bfloat16* h = (__hip_bfloat16*)p;  p += (size_t)N_NODES * OUT_F * 2;
  float* s_src = (float*)p;                p += (size_t)N_NODES * 4;
  float* s_dst = (float*)p;                p += (size_t)N_NODES * 4;
  unsigned int* staged = (unsigned int*)p; p += (size_t)N_EDGES * 4;
  int* bctr = (int*)p;                     p += (size_t)(NB * 32) * 4;
  int* bstart = (int*)p;                   p += (size_t)(NB + 1) * 4 + 12;
  __hip_bfloat16* wt = (__hip_bfloat16*)p; p += (size_t)OUT_F * IN_F * 2;
  (void)bctr;

  // scratch in d_out (fully overwritten by sort_aggregate afterwards):
  // cnt2d NB*NBLK2*4 = 1.6 MB at offset 0, pt at offset 8 MB (6.3 KB).
  int* cnt2d = (int*)d_out;
  int* pt = (int*)((char*)d_out + (size_t)8 * 1024 * 1024);

  wt_kernel<<<OUT_F, 256, 0, stream>>>(W, wt);
  gemm_h_kernel<<<(N_NODES + 63) / 64, 256, 0, stream>>>(in, wt, a, h, s_src,
                                                         s_dst);
  hist2d_kernel<<<NBLK2, 512, 0, stream>>>(src4, cnt2d);
  scan1_kernel<<<NB, 256, 0, stream>>>(cnt2d, pt);
  scan2_kernel<<<1, 256, 0, stream>>>(pt, bstart);
  scatter2_kernel<<<NBLK2, 512, 0, stream>>>(src4, dst4, cnt2d, pt, staged);
  sort_aggregate_kernel<<<NB, 512, 0, stream>>>(bstart, staged, s_src, s_dst,
                                                h, out);
}